// Round 12
// baseline (148.554 us; speedup 1.0000x reference)
//
#include <hip/hip_runtime.h>
#include <hip/hip_cooperative_groups.h>
#include <math.h>

namespace cg = cooperative_groups;

// Problem constants (fixed by the reference): x,y are [4, 64, 64, 64] fp32.
constexpr int B_   = 4;
constexpr int C_   = 64;
constexpr int HW   = 4096;         // N = 64*64
constexpr int ROWS = B_ * HW;      // 16384

constexpr float SIGMA    = 0.1f;
constexpr float EPS_MIN  = 1e-5f;
constexpr float EPS_NORM = 1e-12f;
constexpr float LOG2E    = 1.44269504088896340736f;

// Fused cooperative kernel: grid 256 blocks x 1024 threads = 1 block/CU
// (132 KB LDS caps at 1), all co-resident -> grid.sync() legal.
// Phase 0: normalize (8 lanes/point, shfl reduce), write bf16 xn (-2x) / yn.
// Phase 1: sweep-1 min d^2 -> block-local dmin (block owns XR=64 x-rows,
//          16 waves split all 4096 y 16-ways, wave-private LDS dbuf).
// Phase 2: sweep-2 exp2-sum; one atomicAdd per block of sum(1/S + eps).
// Phase 3: thread 0 writes -log(mean).
constexpr int XR  = 64;            // x-rows per block (4 MFMA col-tiles)
constexpr int NW  = 16;            // waves per block
constexpr int YW  = HW / NW;       // 256 y-rows per wave
constexpr int SRW = 32;            // y-rows per wave-private stage (4 KB)
constexpr int NSW = YW / SRW;      // 8 stages per sweep

using short8  = __attribute__((ext_vector_type(8))) short;   // 8 bf16
using floatx4 = __attribute__((ext_vector_type(4))) float;

__device__ inline ushort f2bf(float f) {           // RNE float->bf16
    unsigned u = __float_as_uint(f);
    unsigned r = u + 0x7FFFu + ((u >> 16) & 1u);
    return (ushort)(r >> 16);
}

__global__ __launch_bounds__(1024, 4)
void fused_kernel(const float* __restrict__ x, const float* __restrict__ y,
                  ushort* __restrict__ xn, ushort* __restrict__ yn,
                  float* __restrict__ total, float* __restrict__ out) {
    __shared__ short8 stg[NW][2][SRW * 8];         // wave-private dbuf, 128 KB
    __shared__ float  red[NW][XR];                 // 4 KB
    __shared__ float  dmf[XR];

    const int tid  = threadIdx.x;
    const int wid  = tid >> 6;                     // 0..15
    const int lane = tid & 63;
    const int lrow = lane & 15;                    // x-col within tile
    const int kgrp = lane >> 4;                    // k-group 0..3
    const int blk  = blockIdx.x;

    cg::grid_group grid = cg::this_grid();

    // ---------------- phase 0: normalize (all 262144 threads) ----------
    {
        int g   = blk * 1024 + tid;
        int p   = g >> 3;                          // point 0..32767
        int oct = g & 7;                           // channel octet
        if (g == 0) *total = 0.0f;
        const float* src; ushort* dst; int q; float sgn;
        if (p < ROWS) { src = x; dst = xn; q = p; sgn = -2.0f; }
        else          { src = y; dst = yn; q = p - ROWS; sgn = 1.0f; }
        int b = q >> 12;
        int n = q & (HW - 1);
        const float* base = src + (size_t)(b * C_) * HW + n;
        float v[8];
        float ss = 0.0f;
#pragma unroll
        for (int j = 0; j < 8; ++j) {
            v[j] = base[(oct * 8 + j) * HW];       // coalesced over n
            ss = fmaf(v[j], v[j], ss);
        }
#pragma unroll
        for (int o = 1; o < 8; o <<= 1) ss += __shfl_xor(ss, o);
        float scale = sgn / fmaxf(sqrtf(ss), EPS_NORM);
        short8 pk;
#pragma unroll
        for (int j = 0; j < 8; ++j) pk[j] = (short)f2bf(v[j] * scale);
        ((short8*)(dst + (size_t)q * C_))[oct] = pk;
    }
    grid.sync();                                   // xn/yn visible device-wide

    // ---------------- GEMM-phase setup ----------------
    const int b     = blk >> 6;                    // 64 blocks per batch
    const int nbase = (blk & 63) * XR;

    // x B-fragments (pre-scaled by -2): 4 tiles x (k 0..31, k 32..63).
    const ushort* xb = xn + (size_t)(b * HW + nbase) * C_;
    short8 xf0[4], xf1[4];
#pragma unroll
    for (int xt = 0; xt < 4; ++xt) {
        xf0[xt] = *(const short8*)(xb + (xt * 16 + lrow) * C_ + kgrp * 8);
        xf1[xt] = *(const short8*)(xb + (xt * 16 + lrow) * C_ + 32 + kgrp * 8);
    }

    // This wave's y-sixteenth, in 16B units (8 units per y-row).
    const short8* yq = (const short8*)(yn + (size_t)(b * HW + wid * YW) * C_);
    // Staging: lane handles units g*64+lane (g=0..3) per stage. Swizzled
    // write slot: row = g*8+(lane>>3), slot = lane&7; (row&7) == lane>>3.
    const int wbase = (lane >> 3) * 8 + ((lane & 7) ^ (lane >> 3));

    short8 v[4];
    float m2[4] = {INFINITY, INFINITY, INFINITY, INFINITY};

    // ---------------- phase 1: sweep min d^2 ----------------
#pragma unroll
    for (int g = 0; g < 4; ++g) v[g] = yq[g * 64 + lane];
#pragma unroll
    for (int g = 0; g < 4; ++g) stg[wid][0][g * 64 + wbase] = v[g];

    for (int s = 0; s < NSW; ++s) {
        int cur = s & 1;
        if (s + 1 < NSW) {                         // issue-early (T14)
#pragma unroll
            for (int g = 0; g < 4; ++g) v[g] = yq[(s + 1) * 256 + g * 64 + lane];
        }
#pragma unroll
        for (int yt = 0; yt < 2; ++yt) {
            int p = yt * 16 + lrow, q = p & 7;
            short8 ya0 = stg[wid][cur][p * 8 + (kgrp ^ q)];         // k 0..31
            short8 ya1 = stg[wid][cur][p * 8 + ((kgrp + 4) ^ q)];   // k 32..63
#pragma unroll
            for (int xt = 0; xt < 4; ++xt) {
                floatx4 acc = {2.0f, 2.0f, 2.0f, 2.0f};
                acc = __builtin_amdgcn_mfma_f32_16x16x32_bf16(ya0, xf0[xt], acc, 0, 0, 0);
                acc = __builtin_amdgcn_mfma_f32_16x16x32_bf16(ya1, xf1[xt], acc, 0, 0, 0);
                // nested for v_min3 fusion
                m2[xt] = fminf(fminf(fminf(acc[0], acc[1]), acc[2]),
                               fminf(acc[3], m2[xt]));
            }
        }
        if (s + 1 < NSW) {                         // write-late (T14)
#pragma unroll
            for (int g = 0; g < 4; ++g) stg[wid][cur ^ 1][g * 64 + wbase] = v[g];
        }
    }

    // Combine the 4 k-groups, then the 16 waves (disjoint y-subsets).
#pragma unroll
    for (int off = 16; off < 64; off <<= 1)
#pragma unroll
        for (int xt = 0; xt < 4; ++xt)
            m2[xt] = fminf(m2[xt], __shfl_xor(m2[xt], off));
    if (kgrp == 0)
#pragma unroll
        for (int xt = 0; xt < 4; ++xt) red[wid][xt * 16 + lrow] = m2[xt];
    __syncthreads();
    if (tid < XR) {
        float m = red[0][tid];
#pragma unroll
        for (int w = 1; w < NW; ++w) m = fminf(m, red[w][tid]);
        dmf[tid] = sqrtf(fmaxf(m, 0.0f));          // dmin
    }
    __syncthreads();

    float kk2[4], c02[4];
#pragma unroll
    for (int xt = 0; xt < 4; ++xt) {
        float dm = dmf[xt * 16 + lrow];
        kk2[xt] = LOG2E / (SIGMA * (dm + EPS_MIN));
        c02[xt] = dm * kk2[xt];
    }

    // ---------------- phase 2: sweep exp2-sum ----------------
    float s2[4] = {0.0f, 0.0f, 0.0f, 0.0f};
#pragma unroll
    for (int g = 0; g < 4; ++g) v[g] = yq[g * 64 + lane];
#pragma unroll
    for (int g = 0; g < 4; ++g) stg[wid][0][g * 64 + wbase] = v[g];

    for (int s = 0; s < NSW; ++s) {
        int cur = s & 1;
        if (s + 1 < NSW) {
#pragma unroll
            for (int g = 0; g < 4; ++g) v[g] = yq[(s + 1) * 256 + g * 64 + lane];
        }
#pragma unroll
        for (int yt = 0; yt < 2; ++yt) {
            int p = yt * 16 + lrow, q = p & 7;
            short8 ya0 = stg[wid][cur][p * 8 + (kgrp ^ q)];
            short8 ya1 = stg[wid][cur][p * 8 + ((kgrp + 4) ^ q)];
#pragma unroll
            for (int xt = 0; xt < 4; ++xt) {
                floatx4 acc = {2.0f, 2.0f, 2.0f, 2.0f};
                acc = __builtin_amdgcn_mfma_f32_16x16x32_bf16(ya0, xf0[xt], acc, 0, 0, 0);
                acc = __builtin_amdgcn_mfma_f32_16x16x32_bf16(ya1, xf1[xt], acc, 0, 0, 0);
                float d0 = __builtin_amdgcn_sqrtf(acc[0]);   // d^2 >= ~1.1
                float d1 = __builtin_amdgcn_sqrtf(acc[1]);
                float d2 = __builtin_amdgcn_sqrtf(acc[2]);
                float d3 = __builtin_amdgcn_sqrtf(acc[3]);
                s2[xt] += __builtin_amdgcn_exp2f(fmaf(-kk2[xt], d0, c02[xt]));
                s2[xt] += __builtin_amdgcn_exp2f(fmaf(-kk2[xt], d1, c02[xt]));
                s2[xt] += __builtin_amdgcn_exp2f(fmaf(-kk2[xt], d2, c02[xt]));
                s2[xt] += __builtin_amdgcn_exp2f(fmaf(-kk2[xt], d3, c02[xt]));
            }
        }
        if (s + 1 < NSW) {
#pragma unroll
            for (int g = 0; g < 4; ++g) stg[wid][cur ^ 1][g * 64 + wbase] = v[g];
        }
    }

#pragma unroll
    for (int off = 16; off < 64; off <<= 1)
#pragma unroll
        for (int xt = 0; xt < 4; ++xt)
            s2[xt] += __shfl_xor(s2[xt], off);
    if (kgrp == 0)
#pragma unroll
        for (int xt = 0; xt < 4; ++xt) red[wid][xt * 16 + lrow] = s2[xt];
    __syncthreads();

    // Block partial of sum(1/S + eps) -> one atomicAdd.
    if (tid < 64) {
        float Ssum = red[0][tid];
#pragma unroll
        for (int w = 1; w < NW; ++w) Ssum += red[w][tid];
        float acc = __builtin_amdgcn_rcpf(Ssum) + EPS_MIN;
#pragma unroll
        for (int off = 32; off > 0; off >>= 1) acc += __shfl_down(acc, off);
        if (tid == 0) atomicAdd(total, acc);
    }

    // ---------------- phase 3: final scalar ----------------
    grid.sync();
    if (blk == 0 && tid == 0) out[0] = -logf(total[0] / (float)ROWS);
}

// ---------------------------------------------------------------------------
extern "C" void kernel_launch(void* const* d_in, const int* in_sizes, int n_in,
                              void* d_out, int out_size, void* d_ws, size_t ws_size,
                              hipStream_t stream) {
    const float* x = (const float*)d_in[0];
    const float* y = (const float*)d_in[1];
    float* out = (float*)d_out;

    char* ws = (char*)d_ws;
    size_t nrm_bytes = (size_t)ROWS * C_ * sizeof(ushort);   // 2 MB each
    ushort* xn    = (ushort*)(ws);
    ushort* yn    = (ushort*)(ws + nrm_bytes);
    float*  total = (float*)(ws + 2 * nrm_bytes);

    void* args[] = { (void*)&x, (void*)&y, (void*)&xn, (void*)&yn,
                     (void*)&total, (void*)&out };
    hipLaunchCooperativeKernel((const void*)fused_kernel, dim3(256), dim3(1024),
                               args, 0, stream);
}

// Round 13
// 95.266 us; speedup vs baseline: 1.5594x; 1.5594x over previous
//
#include <hip/hip_runtime.h>
#include <math.h>

// Problem constants (fixed by the reference): x,y are [4, 64, 64, 64] fp32.
constexpr int B_   = 4;
constexpr int C_   = 64;
constexpr int HW   = 4096;         // N = 64*64
constexpr int ROWS = B_ * HW;      // 16384
constexpr int GRID = 256;          // main grid = ROWS / XR

constexpr float SIGMA    = 0.1f;
constexpr float EPS_MIN  = 1e-5f;
constexpr float EPS_NORM = 1e-12f;
constexpr float LOG2E    = 1.44269504088896340736f;

// R10 geometry (verified 93.3us): block owns XR=64 x-rows x ALL 4096 y of
// one batch; 16 waves split y 16-ways, wave-private LDS dbuf stages.
// NEW: staging via global_load_lds (linear DMA) from PRE-SWIZZLED yn
// (slot XOR baked into global layout by nrm) + counted vmcnt(4) waits.
constexpr int XR  = 64;            // x-rows per block (4 MFMA col-tiles)
constexpr int NW  = 16;            // waves per block
constexpr int YW  = HW / NW;       // 256 y-rows per wave
constexpr int SRW = 32;            // y-rows per wave-private stage (4 KB)
constexpr int NSW = YW / SRW;      // 8 stages per sweep

using short8  = __attribute__((ext_vector_type(8))) short;   // 8 bf16
using floatx4 = __attribute__((ext_vector_type(4))) float;

__device__ inline ushort f2bf(float f) {           // RNE float->bf16
    unsigned u = __float_as_uint(f);
    unsigned r = u + 0x7FFFu + ((u >> 16) & 1u);
    return (ushort)(r >> 16);
}

// Async global->LDS, 16B per lane: per-lane global src, wave-uniform LDS
// base (DMA writes base + lane*16).  vmcnt-counted.
__device__ inline void gload16(const ushort* g, void* lds) {
    __builtin_amdgcn_global_load_lds(
        (const __attribute__((address_space(1))) void*)g,
        (__attribute__((address_space(3))) void*)lds, 16, 0, 0);
}

#define WAIT_VMCNT(n) asm volatile("s_waitcnt vmcnt(" #n ")" ::: "memory")

// ---------------------------------------------------------------------------
// Normalize along C, write bf16 [B][N][C] point-major.
// xn pre-scaled by -2 (exact in bf16) so MFMA with C-init=2 emits d^2
// directly (verified R9/R10).  yn rows are written with the staging swizzle
// BAKED IN: 16B slot s of row n lands at slot s ^ (n&7)  (rule #21: linear
// DMA + swizzled read requires pre-swizzled source).
__global__ __launch_bounds__(256) void nrm_kernel(const float* __restrict__ x,
                                                  const float* __restrict__ y,
                                                  ushort* __restrict__ xn,
                                                  ushort* __restrict__ yn,
                                                  float* __restrict__ total,
                                                  unsigned* __restrict__ cnt) {
    int p = blockIdx.x * 256 + threadIdx.x;        // 0 .. 2*ROWS-1
    if (p == 0) { *total = 0.0f; *cnt = 0u; }
    const float* src; ushort* dst; int q; float sgn; bool isy;
    if (p < ROWS) { src = x; dst = xn; q = p; sgn = -2.0f; isy = false; }
    else          { src = y; dst = yn; q = p - ROWS; sgn = 1.0f; isy = true; }
    int b = q >> 12;
    int n = q & (HW - 1);
    const float* base = src + (size_t)(b * C_) * HW + n;  // coalesced over n
    float v[C_];
    float ss = 0.0f;
#pragma unroll
    for (int c = 0; c < C_; ++c) {
        v[c] = base[(size_t)c * HW];
        ss = fmaf(v[c], v[c], ss);
    }
    float scale = sgn / fmaxf(sqrtf(ss), EPS_NORM);
    short8* o = (short8*)(dst + (size_t)q * C_);
    int sw = isy ? (n & 7) : 0;                    // y: bake staging swizzle
#pragma unroll
    for (int c8 = 0; c8 < C_ / 8; ++c8) {
        short8 pk;
#pragma unroll
        for (int j = 0; j < 8; ++j) pk[j] = (short)f2bf(v[c8 * 8 + j] * scale);
        o[c8 ^ sw] = pk;
    }
}

// ---------------------------------------------------------------------------
// Fused main. Swapped-operand MFMA (A=y, B=-2x, C=2): D = d^2; D col = x
// point (lane&15), D row = y point.  Sweep 1: min d^2 -> block-local dmin.
// Sweep 2: S_row = sum exp2((dmin-d)*kk2).  One atomicAdd of sum(1/S+eps)
// per block; LAST block (threadfence+counter) writes -log(mean) to out.
__global__ __launch_bounds__(1024, 4) void main_kernel(const ushort* __restrict__ xn,
                                                       const ushort* __restrict__ yn,
                                                       float* __restrict__ total,
                                                       unsigned* __restrict__ cnt,
                                                       float* __restrict__ out) {
    __shared__ short8 stg[NW][2][SRW * 8];         // wave-private dbuf, 128 KB
    __shared__ float  red[NW][XR];                 // 4 KB
    __shared__ float  dmf[XR];

    const int tid  = threadIdx.x;
    const int wid  = tid >> 6;                     // 0..15
    const int lane = tid & 63;
    const int lrow = lane & 15;                    // x-col within tile
    const int kgrp = lane >> 4;                    // k-group 0..3

    const int blk   = blockIdx.x;
    const int b     = blk >> 6;                    // 64 blocks per batch
    const int nbase = (blk & 63) * XR;

    // x B-fragments (pre-scaled by -2): 4 tiles x (k 0..31, k 32..63).
    const ushort* xb = xn + (size_t)(b * HW + nbase) * C_;
    short8 xf0[4], xf1[4];
#pragma unroll
    for (int xt = 0; xt < 4; ++xt) {
        xf0[xt] = *(const short8*)(xb + (xt * 16 + lrow) * C_ + kgrp * 8);
        xf1[xt] = *(const short8*)(xb + (xt * 16 + lrow) * C_ + 32 + kgrp * 8);
    }

    // This wave's y-sixteenth (pre-swizzled rows), per-lane DMA source.
    const ushort* yb = yn + (size_t)(b * HW + wid * YW) * C_ + lane * 8;

    // Issue one 4KB stage as 4 x (64 lanes x 16B) DMAs into buffer `buf`.
#define ISSUE(s, buf) do {                                              \
        const ushort* gp_ = yb + (size_t)(s) * SRW * C_;                \
        _Pragma("unroll")                                               \
        for (int g_ = 0; g_ < 4; ++g_)                                  \
            gload16(gp_ + g_ * 64 * 8, (void*)&stg[wid][buf][g_ * 64]); \
    } while (0)

    float m2[4] = {INFINITY, INFINITY, INFINITY, INFINITY};

    // ---------------- sweep 1: min d^2 ----------------
    ISSUE(0, 0);
    for (int s = 0; s < NSW; ++s) {
        int cur = s & 1;
        if (s + 1 < NSW) { ISSUE(s + 1, cur ^ 1); WAIT_VMCNT(4); }
        else             { WAIT_VMCNT(0); }
        __builtin_amdgcn_sched_barrier(0);
#pragma unroll
        for (int yt = 0; yt < 2; ++yt) {
            int p = yt * 16 + lrow, q = p & 7;
            short8 ya0 = stg[wid][cur][p * 8 + (kgrp ^ q)];         // k 0..31
            short8 ya1 = stg[wid][cur][p * 8 + ((kgrp + 4) ^ q)];   // k 32..63
#pragma unroll
            for (int xt = 0; xt < 4; ++xt) {
                floatx4 acc = {2.0f, 2.0f, 2.0f, 2.0f};
                acc = __builtin_amdgcn_mfma_f32_16x16x32_bf16(ya0, xf0[xt], acc, 0, 0, 0);
                acc = __builtin_amdgcn_mfma_f32_16x16x32_bf16(ya1, xf1[xt], acc, 0, 0, 0);
                m2[xt] = fminf(fminf(fminf(acc[0], acc[1]), acc[2]),
                               fminf(acc[3], m2[xt]));
            }
        }
    }

    // Combine the 4 k-groups, then the 16 waves (disjoint y-subsets).
#pragma unroll
    for (int off = 16; off < 64; off <<= 1)
#pragma unroll
        for (int xt = 0; xt < 4; ++xt)
            m2[xt] = fminf(m2[xt], __shfl_xor(m2[xt], off));
    if (kgrp == 0)
#pragma unroll
        for (int xt = 0; xt < 4; ++xt) red[wid][xt * 16 + lrow] = m2[xt];
    __syncthreads();
    if (tid < XR) {
        float m = red[0][tid];
#pragma unroll
        for (int w = 1; w < NW; ++w) m = fminf(m, red[w][tid]);
        dmf[tid] = sqrtf(fmaxf(m, 0.0f));          // dmin
    }
    __syncthreads();

    float kk2[4], c02[4];
#pragma unroll
    for (int xt = 0; xt < 4; ++xt) {
        float dm = dmf[xt * 16 + lrow];
        kk2[xt] = LOG2E / (SIGMA * (dm + EPS_MIN));
        c02[xt] = dm * kk2[xt];
    }

    // ---------------- sweep 2: exp2-sum ----------------
    float s2[4] = {0.0f, 0.0f, 0.0f, 0.0f};
    ISSUE(0, 0);
    for (int s = 0; s < NSW; ++s) {
        int cur = s & 1;
        if (s + 1 < NSW) { ISSUE(s + 1, cur ^ 1); WAIT_VMCNT(4); }
        else             { WAIT_VMCNT(0); }
        __builtin_amdgcn_sched_barrier(0);
#pragma unroll
        for (int yt = 0; yt < 2; ++yt) {
            int p = yt * 16 + lrow, q = p & 7;
            short8 ya0 = stg[wid][cur][p * 8 + (kgrp ^ q)];
            short8 ya1 = stg[wid][cur][p * 8 + ((kgrp + 4) ^ q)];
#pragma unroll
            for (int xt = 0; xt < 4; ++xt) {
                floatx4 acc = {2.0f, 2.0f, 2.0f, 2.0f};
                acc = __builtin_amdgcn_mfma_f32_16x16x32_bf16(ya0, xf0[xt], acc, 0, 0, 0);
                acc = __builtin_amdgcn_mfma_f32_16x16x32_bf16(ya1, xf1[xt], acc, 0, 0, 0);
                float d0 = __builtin_amdgcn_sqrtf(acc[0]);   // d^2 >= ~1.1
                float d1 = __builtin_amdgcn_sqrtf(acc[1]);
                float d2 = __builtin_amdgcn_sqrtf(acc[2]);
                float d3 = __builtin_amdgcn_sqrtf(acc[3]);
                s2[xt] += __builtin_amdgcn_exp2f(fmaf(-kk2[xt], d0, c02[xt]));
                s2[xt] += __builtin_amdgcn_exp2f(fmaf(-kk2[xt], d1, c02[xt]));
                s2[xt] += __builtin_amdgcn_exp2f(fmaf(-kk2[xt], d2, c02[xt]));
                s2[xt] += __builtin_amdgcn_exp2f(fmaf(-kk2[xt], d3, c02[xt]));
            }
        }
    }
#undef ISSUE

#pragma unroll
    for (int off = 16; off < 64; off <<= 1)
#pragma unroll
        for (int xt = 0; xt < 4; ++xt)
            s2[xt] += __shfl_xor(s2[xt], off);
    if (kgrp == 0)
#pragma unroll
        for (int xt = 0; xt < 4; ++xt) red[wid][xt * 16 + lrow] = s2[xt];
    __syncthreads();

    // Block partial of sum(1/S + eps) -> one atomicAdd; last block finishes.
    if (tid < 64) {
        float Ssum = (tid < XR) ? red[0][tid] : 0.0f;
        if (tid < XR)
#pragma unroll
            for (int w = 1; w < NW; ++w) Ssum += red[w][tid];
        float acc = (tid < XR) ? (__builtin_amdgcn_rcpf(Ssum) + EPS_MIN) : 0.0f;
#pragma unroll
        for (int off = 32; off > 0; off >>= 1) acc += __shfl_down(acc, off);
        if (tid == 0) {
            atomicAdd(total, acc);
            __threadfence();
            unsigned done = atomicAdd(cnt, 1u);
            if (done == GRID - 1) {                // last block
                __threadfence();
                float t = atomicAdd(total, 0.0f);  // coherent RMW read
                out[0] = -logf(t / (float)ROWS);
            }
        }
    }
}

// ---------------------------------------------------------------------------
extern "C" void kernel_launch(void* const* d_in, const int* in_sizes, int n_in,
                              void* d_out, int out_size, void* d_ws, size_t ws_size,
                              hipStream_t stream) {
    const float* x = (const float*)d_in[0];
    const float* y = (const float*)d_in[1];
    float* out = (float*)d_out;

    char* ws = (char*)d_ws;
    size_t nrm_bytes = (size_t)ROWS * C_ * sizeof(ushort);   // 2 MB each
    ushort*   xn    = (ushort*)(ws);
    ushort*   yn    = (ushort*)(ws + nrm_bytes);
    float*    total = (float*)(ws + 2 * nrm_bytes);
    unsigned* cnt   = (unsigned*)(ws + 2 * nrm_bytes + 16);

    hipLaunchKernelGGL(nrm_kernel, dim3(2 * ROWS / 256), dim3(256), 0, stream,
                       x, y, xn, yn, total, cnt);
    hipLaunchKernelGGL(main_kernel, dim3(GRID), dim3(1024), 0, stream,
                       xn, yn, total, cnt, out);
}